// Round 1
// baseline (22299.539 us; speedup 1.0000x reference)
//
#include <hip/hip_runtime.h>

// GRUPlant: B=256, T_IN=512, T_TGT=256, N_IN=64, N_PV=16, H=256, EMB=32, N_SC=4
// Round 0: fp32 VALU baseline. Kernel-per-step graph:
//   - encoder: 513 launches, each fusing layer0(t) and layer1(t-1) (disjoint ping-pong buffers)
//   - decoder: 256 x { dec0(s), dec1(s), y(s) }  (y feedback forces 3 sequential stages/step)
// Weights pre-transposed once per call into ws, k4-major float4 layout -> coalesced lane reads.

#define BB 256
#define T_INN 512
#define T_TGTT 256
#define N_INN 64
#define N_PVV 16
#define HH 256
#define EMBB 32
#define G3 768

enum { JOB_ENC = 0, JOB_DEC0 = 1, JOB_DEC1 = 2 };

__device__ __forceinline__ float dot4(float4 a, float4 b) {
    return a.x*b.x + a.y*b.y + a.z*b.z + a.w*b.w;
}

__device__ __forceinline__ float sigm(float x) { return 1.f / (1.f + __expf(-x)); }
// tanh via exp; safe at extremes (exp->0 gives -1, exp->inf gives +1)
__device__ __forceinline__ float tanh_fast(float x) { return 1.f - 2.f / (__expf(2.f * x) + 1.f); }

// Transpose W (768 x K, row-major) into k4-major float4 layout:
// WT4[k4*768 + grow] = float4{ W[grow][4k4 .. 4k4+3] }
__global__ __launch_bounds__(256) void transpose_w(const float* __restrict__ W,
                                                   float* __restrict__ WT,
                                                   int K, int total4) {
    int idx = blockIdx.x * 256 + threadIdx.x;
    if (idx >= total4) return;
    int grow = idx % G3;
    int k4 = idx / G3;
    float4 v = *(const float4*)(W + (size_t)grow * K + k4 * 4);
    ((float4*)WT)[idx] = v;
}

// Generic GRU step. Tile = 16 rows x 32 h-cols, 256 threads:
// thread: c = tid&31 (h-col), rg = tid>>5 (2 batch rows each).
__global__ __launch_bounds__(256) void gru_step(
    int job, int t,
    const float* __restrict__ WihT_A, const float* __restrict__ WhhT_A,
    const float* __restrict__ bihA, const float* __restrict__ bhhA,
    const float* __restrict__ WihT_B, const float* __restrict__ WhhT_B,
    const float* __restrict__ bihB, const float* __restrict__ bhhB,
    const float* __restrict__ x_cv, const float* __restrict__ x_tgt,
    const int* __restrict__ scenario, const float* __restrict__ emb,
    const float* __restrict__ pv_src, int pv_stride,
    float* __restrict__ h0buf, float* __restrict__ h1buf)
{
    __shared__ float Ainf[16 * 256];
    __shared__ float Hinf[16 * 256];

    int bx = blockIdx.x;
    int tid = threadIdx.x;

    const float *WihT, *WhhT, *bih, *bhh, *Hin;
    const float* Aprev = nullptr;
    float* Hout;
    int Kx, akind, tileid; // akind: 0=x_cv+emb, 1=h-buffer, 2=x_tgt+pv

    if (job == JOB_ENC) {
        if (bx < 128) {
            if (t == T_INN) return;              // no layer0 work at t=512
            tileid = bx; akind = 0; Kx = 96;
            WihT = WihT_A; WhhT = WhhT_A; bih = bihA; bhh = bhhA;
            Hin  = h0buf + (t & 1) * (BB * HH);
            Hout = h0buf + ((t + 1) & 1) * (BB * HH);
        } else {
            if (t == 0) return;                  // no layer1 work at t=0
            tileid = bx - 128; akind = 1; Kx = 256;
            WihT = WihT_B; WhhT = WhhT_B; bih = bihB; bhh = bhhB;
            Aprev = h0buf + (t & 1) * (BB * HH);         // h0(t-1)
            Hin   = h1buf + ((t + 1) & 1) * (BB * HH);   // h1(t-2)
            Hout  = h1buf + (t & 1) * (BB * HH);         // h1(t-1)
        }
    } else if (job == JOB_DEC0) {
        tileid = bx; akind = 2; Kx = 80;
        WihT = WihT_A; WhhT = WhhT_A; bih = bihA; bhh = bhhA;
        Hin  = h0buf + (t & 1) * (BB * HH);
        Hout = h0buf + ((t + 1) & 1) * (BB * HH);
    } else { // JOB_DEC1
        tileid = bx; akind = 1; Kx = 256;
        WihT = WihT_A; WhhT = WhhT_A; bih = bihA; bhh = bhhA;
        Aprev = h0buf + ((t + 1) & 1) * (BB * HH);       // d0(t)
        Hin   = h1buf + (t & 1) * (BB * HH);
        Hout  = h1buf + ((t + 1) & 1) * (BB * HH);
    }

    int rt = tileid >> 3, ct = tileid & 7;
    int r0 = rt * 16, c0 = ct * 32;

    // ---- stage A into LDS (row stride 256 floats) ----
    if (akind == 0) {
        for (int i = tid; i < 16 * 96; i += 256) {
            int r = i / 96, k = i - r * 96;
            float v = (k < 64)
                ? x_cv[(size_t)(r0 + r) * (T_INN * N_INN) + (size_t)t * N_INN + k]
                : emb[scenario[r0 + r] * EMBB + (k - 64)];
            Ainf[r * 256 + k] = v;
        }
    } else if (akind == 1) {
        for (int i = tid; i < 4096; i += 256)
            Ainf[i] = Aprev[(size_t)(r0 + (i >> 8)) * HH + (i & 255)];
    } else {
        for (int i = tid; i < 16 * 80; i += 256) {
            int r = i / 80, k = i - r * 80;
            float v = (k < 64)
                ? x_tgt[(size_t)(r0 + r) * (T_TGTT * N_INN) + (size_t)t * N_INN + k]
                : pv_src[(size_t)(r0 + r) * pv_stride + (k - 64)];
            Ainf[r * 256 + k] = v;
        }
    }
    // ---- stage H into LDS ----
    for (int i = tid; i < 4096; i += 256)
        Hinf[i] = Hin[(size_t)(r0 + (i >> 8)) * HH + (i & 255)];
    __syncthreads();

    int c = tid & 31, rg = tid >> 5;
    int grow = c0 + c;
    const float4* Ain4 = (const float4*)Ainf;
    const float4* Hin4 = (const float4*)Hinf;
    const float4* Wi4 = (const float4*)WihT;
    const float4* Wh4 = (const float4*)WhhT;

    float aR0 = 0.f, aR1 = 0.f, aZ0 = 0.f, aZ1 = 0.f;
    float aNi0 = 0.f, aNi1 = 0.f, aNh0 = 0.f, aNh1 = 0.f;
    int Kx4 = Kx >> 2;
    int rowA = (rg * 2) * 64, rowB = (rg * 2 + 1) * 64;

    for (int k4 = 0; k4 < Kx4; ++k4) {
        float4 wr = Wi4[k4 * G3 + grow];
        float4 wz = Wi4[k4 * G3 + 256 + grow];
        float4 wn = Wi4[k4 * G3 + 512 + grow];
        float4 a0 = Ain4[rowA + k4];
        float4 a1 = Ain4[rowB + k4];
        aR0 += dot4(a0, wr);  aR1 += dot4(a1, wr);
        aZ0 += dot4(a0, wz);  aZ1 += dot4(a1, wz);
        aNi0 += dot4(a0, wn); aNi1 += dot4(a1, wn);
    }
    for (int k4 = 0; k4 < 64; ++k4) {
        float4 wr = Wh4[k4 * G3 + grow];
        float4 wz = Wh4[k4 * G3 + 256 + grow];
        float4 wn = Wh4[k4 * G3 + 512 + grow];
        float4 h0v = Hin4[rowA + k4];
        float4 h1v = Hin4[rowB + k4];
        aR0 += dot4(h0v, wr);  aR1 += dot4(h1v, wr);
        aZ0 += dot4(h0v, wz);  aZ1 += dot4(h1v, wz);
        aNh0 += dot4(h0v, wn); aNh1 += dot4(h1v, wn);
    }

    float bir = bihA[0]; // placate compiler ordering; real biases below
    (void)bir;
    float b_r = bih[grow] + bhh[grow];
    float b_z = bih[256 + grow] + bhh[256 + grow];
    float b_ni = bih[512 + grow];
    float b_nh = bhh[512 + grow];

#pragma unroll
    for (int j = 0; j < 2; ++j) {
        int rl = rg * 2 + j;
        float aR = j ? aR1 : aR0, aZ = j ? aZ1 : aZ0;
        float aNi = j ? aNi1 : aNi0, aNh = j ? aNh1 : aNh0;
        float r = sigm(aR + b_r);
        float z = sigm(aZ + b_z);
        float n = tanh_fast(aNi + b_ni + r * (aNh + b_nh));
        float hp = Hinf[rl * 256 + grow];
        Hout[(size_t)(r0 + rl) * HH + grow] = (1.f - z) * n + z * hp;
    }
}

// y(s) = fc2(relu(fc1(h1(s)))) for all rows; writes d_out[:, s, :].
__global__ __launch_bounds__(256) void y_step(
    int s,
    const float* __restrict__ h1buf,
    const float* __restrict__ fc1W, const float* __restrict__ fc1b,
    const float* __restrict__ fc2W, const float* __restrict__ fc2b,
    float* __restrict__ out)
{
    __shared__ float Hy[16 * 256];
    __shared__ float Fb[16 * 128];
    int tid = threadIdx.x;
    int r0 = blockIdx.x * 16;
    const float* h1 = h1buf + ((s + 1) & 1) * (BB * HH);

    for (int i = tid; i < 4096; i += 256)
        Hy[i] = h1[(size_t)(r0 + (i >> 8)) * HH + (i & 255)];
    __syncthreads();

    { // fc1: 16 rows x 128 outs, relu
        int f = tid & 127, rh = tid >> 7; // rows rh*8 .. rh*8+7
        const float4* w4 = (const float4*)(fc1W + (size_t)f * 256);
        const float4* Hy4 = (const float4*)Hy;
        float acc[8] = {0, 0, 0, 0, 0, 0, 0, 0};
        for (int k4 = 0; k4 < 64; ++k4) {
            float4 w = w4[k4];
#pragma unroll
            for (int j = 0; j < 8; ++j)
                acc[j] += dot4(Hy4[(rh * 8 + j) * 64 + k4], w);
        }
        float bb = fc1b[f];
#pragma unroll
        for (int j = 0; j < 8; ++j)
            Fb[(rh * 8 + j) * 128 + f] = fmaxf(acc[j] + bb, 0.f);
    }
    __syncthreads();

    { // fc2: 16 rows x 16 outs
        int o = tid & 15, r = tid >> 4;
        const float4* w4 = (const float4*)(fc2W + (size_t)o * 128);
        const float4* Fb4 = (const float4*)(Fb + r * 128);
        float acc = 0.f;
        for (int k4 = 0; k4 < 32; ++k4)
            acc += dot4(Fb4[k4], w4[k4]);
        out[(size_t)(r0 + r) * (T_TGTT * N_PVV) + (size_t)s * N_PVV + o] = acc + fc2b[o];
    }
}

extern "C" void kernel_launch(void* const* d_in, const int* in_sizes, int n_in,
                              void* d_out, int out_size, void* d_ws, size_t ws_size,
                              hipStream_t stream)
{
    const float* x_cv    = (const float*)d_in[0];
    const float* x_tgt   = (const float*)d_in[1];
    const float* pv_init = (const float*)d_in[2];
    const int*   scen    = (const int*)d_in[3];
    const float* emb     = (const float*)d_in[4];
    const float* eWih0 = (const float*)d_in[5];
    const float* eWhh0 = (const float*)d_in[6];
    const float* ebih0 = (const float*)d_in[7];
    const float* ebhh0 = (const float*)d_in[8];
    const float* eWih1 = (const float*)d_in[9];
    const float* eWhh1 = (const float*)d_in[10];
    const float* ebih1 = (const float*)d_in[11];
    const float* ebhh1 = (const float*)d_in[12];
    const float* dWih0 = (const float*)d_in[13];
    const float* dWhh0 = (const float*)d_in[14];
    const float* dbih0 = (const float*)d_in[15];
    const float* dbhh0 = (const float*)d_in[16];
    const float* dWih1 = (const float*)d_in[17];
    const float* dWhh1 = (const float*)d_in[18];
    const float* dbih1 = (const float*)d_in[19];
    const float* dbhh1 = (const float*)d_in[20];
    const float* fc1W = (const float*)d_in[21];
    const float* fc1b = (const float*)d_in[22];
    const float* fc2W = (const float*)d_in[23];
    const float* fc2b = (const float*)d_in[24];
    float* out = (float*)d_out;

    float* ws = (float*)d_ws;
    float* h0buf = ws;                       // 2 * 65536 floats (ping-pong)
    float* h1buf = ws + 2 * BB * HH;         // 2 * 65536 floats
    float* tw = ws + 4 * BB * HH;
    float* T_eWih0 = tw; tw += (96 / 4) * G3 * 4;
    float* T_eWhh0 = tw; tw += 64 * G3 * 4;
    float* T_eWih1 = tw; tw += 64 * G3 * 4;
    float* T_eWhh1 = tw; tw += 64 * G3 * 4;
    float* T_dWih0 = tw; tw += (80 / 4) * G3 * 4;
    float* T_dWhh0 = tw; tw += 64 * G3 * 4;
    float* T_dWih1 = tw; tw += 64 * G3 * 4;
    float* T_dWhh1 = tw; tw += 64 * G3 * 4;

    // h(-1) = 0 for both layers (parity-0 buffers only; parity-1 written before read)
    hipMemsetAsync(h0buf, 0, BB * HH * sizeof(float), stream);
    hipMemsetAsync(h1buf, 0, BB * HH * sizeof(float), stream);

    auto tp = [&](const float* W, float* WT, int K) {
        int total4 = G3 * (K / 4);
        transpose_w<<<(total4 + 255) / 256, 256, 0, stream>>>(W, WT, K, total4);
    };
    tp(eWih0, T_eWih0, 96);  tp(eWhh0, T_eWhh0, 256);
    tp(eWih1, T_eWih1, 256); tp(eWhh1, T_eWhh1, 256);
    tp(dWih0, T_dWih0, 80);  tp(dWhh0, T_dWhh0, 256);
    tp(dWih1, T_dWih1, 256); tp(dWhh1, T_dWhh1, 256);

    // Encoder: fused layer0(t) + layer1(t-1); t = 0..512 inclusive
    for (int t = 0; t <= T_INN; ++t) {
        gru_step<<<256, 256, 0, stream>>>(JOB_ENC, t,
            T_eWih0, T_eWhh0, ebih0, ebhh0,
            T_eWih1, T_eWhh1, ebih1, ebhh1,
            x_cv, x_tgt, scen, emb, pv_init, N_PVV, h0buf, h1buf);
    }
    // Decoder: d0(s) -> d1(s) -> y(s)
    for (int s = 0; s < T_TGTT; ++s) {
        const float* pv = (s == 0) ? pv_init : (out + (size_t)(s - 1) * N_PVV);
        int pvs = (s == 0) ? N_PVV : (T_TGTT * N_PVV);
        gru_step<<<128, 256, 0, stream>>>(JOB_DEC0, s,
            T_dWih0, T_dWhh0, dbih0, dbhh0,
            T_dWih0, T_dWhh0, dbih0, dbhh0,
            x_cv, x_tgt, scen, emb, pv, pvs, h0buf, h1buf);
        gru_step<<<128, 256, 0, stream>>>(JOB_DEC1, s,
            T_dWih1, T_dWhh1, dbih1, dbhh1,
            T_dWih1, T_dWhh1, dbih1, dbhh1,
            x_cv, x_tgt, scen, emb, pv, pvs, h0buf, h1buf);
        y_step<<<16, 256, 0, stream>>>(s, h1buf, fc1W, fc1b, fc2W, fc2b, out);
    }
}